// Round 7
// baseline (358.827 us; speedup 1.0000x reference)
//
#include <hip/hip_runtime.h>
#include <math.h>

#define BB 64
#define NN 1000
#define CC 64
#define TT 32
#define NCH 40
#define NCHUNKS 25   // NN / NCH

typedef float floatx4 __attribute__((ext_vector_type(4)));

// ---- Fused pass 1: one read of X -> Apart chunk-partials + Gpart chunk-partials ----
// grid = BB * NCHUNKS blocks, 256 threads = (t = tid&31, nl = tid>>5).
__global__ __launch_bounds__(256) void k_p1(const float* __restrict__ X,
                                            const float* __restrict__ U1,
                                            const float* __restrict__ U3,
                                            const float* __restrict__ U2,
                                            float* __restrict__ Apart,
                                            float* __restrict__ Gpart) {
    int b  = blockIdx.x / NCHUNKS;
    int ch = blockIdx.x % NCHUNKS;
    int t  = threadIdx.x & 31;
    int nl = threadIdx.x >> 5;
    int n0 = ch * NCH;

    __shared__ float u2s[CC][NCH + 1];   // 10.5 KB, pad -> stride 41 (conflict-free)
    __shared__ float rls[NCH][TT];       // 5 KB
    __shared__ float buf[8][32][9];      // 9.2 KB

    // stage U2 chunk: u2s[c][n] = U2[c, n0+n]
    for (int k = threadIdx.x; k < CC * NCH; k += 256) {
        int c = k / NCH, n = k % NCH;
        u2s[c][n] = U2[(size_t)c * NN + n0 + n];
    }

    float accA[CC];
#pragma unroll
    for (int c = 0; c < CC; ++c) accA[c] = 0.f;
    float rl[NCH / 8];

    for (int i = 0; i < NCH / 8; ++i) {
        int n = n0 + i * 8 + nl;
        const float* xp = X + ((size_t)(b * NN + n) * CC) * TT + t;
        float u1 = U1[n];
        float r = 0.f;
#pragma unroll
        for (int c = 0; c < CC; ++c) {
            float x = __builtin_nontemporal_load(&xp[c * TT]);
            r += U3[c] * x;
            accA[c] += u1 * x;
        }
        rl[i] = r;
    }

    // stage rhs chunk into LDS
#pragma unroll
    for (int i = 0; i < NCH / 8; ++i) rls[i * 8 + nl][t] = rl[i];
    __syncthreads();  // also covers u2s staging

    // mini-GEMM: thread -> c = tid>>2, s0 = (tid&3)*8; 8 outputs
    {
        int c = threadIdx.x >> 2;
        int s0 = (threadIdx.x & 3) * 8;
        float g[8];
#pragma unroll
        for (int j = 0; j < 8; ++j) g[j] = 0.f;
#pragma unroll 4
        for (int n = 0; n < NCH; ++n) {
            float u2v = u2s[c][n];
            floatx4 r0 = *(const floatx4*)&rls[n][s0];
            floatx4 r1 = *(const floatx4*)&rls[n][s0 + 4];
            g[0] += u2v * r0.x; g[1] += u2v * r0.y;
            g[2] += u2v * r0.z; g[3] += u2v * r0.w;
            g[4] += u2v * r1.x; g[5] += u2v * r1.y;
            g[6] += u2v * r1.z; g[7] += u2v * r1.w;
        }
        float* gp = Gpart + ((size_t)(ch * BB + b) * CC + c) * TT + s0;
        floatx4 v0 = { g[0], g[1], g[2], g[3] };
        floatx4 v1 = { g[4], g[5], g[6], g[7] };
        *(floatx4*)gp = v0;
        *(floatx4*)(gp + 4) = v1;
    }

    // reduce accA over nl: 8 strips of 8 c's through padded LDS
    int t2 = threadIdx.x & 31;
    int j2 = threadIdx.x >> 5;
    for (int strip = 0; strip < 8; ++strip) {
        __syncthreads();
#pragma unroll
        for (int j = 0; j < 8; ++j) buf[nl][t][j] = accA[strip * 8 + j];
        __syncthreads();
        float v = 0.f;
#pragma unroll
        for (int k = 0; k < 8; ++k) v += buf[k][t2][j2];
        Apart[((size_t)(ch * BB + b) * TT + t2) * CC + strip * 8 + j2] = v;
    }
}

// ---- E[b,t,u]: reduce Apart & Gpart -> scores -> sigmoid -> Ve@ -> softmax ----
__global__ __launch_bounds__(1024) void k_E(const float* __restrict__ Apart,
                                            const float* __restrict__ Gpart,
                                            const float* __restrict__ be,
                                            const float* __restrict__ Ve,
                                            float* __restrict__ E) {
    int b = blockIdx.x;
    int tid = threadIdx.x;
    int u = tid & 31;
    int t = tid >> 5;
    __shared__ float As[TT][CC + 1];
    __shared__ float Gs[CC * TT];
    __shared__ float sig[TT][TT];
    __shared__ float e0[TT][TT];

    float a0 = 0.f, a1 = 0.f;
    for (int ch = 0; ch < NCHUNKS; ++ch) {
        const float* ap = Apart + ((size_t)(ch * BB + b) * TT + t) * CC;
        a0 += ap[u];
        a1 += ap[u + 32];
    }
    As[t][u] = a0;
    As[t][u + 32] = a1;

    float g0 = 0.f, g1 = 0.f;
    for (int ch = 0; ch < NCHUNKS; ++ch) {
        const float* gp = Gpart + (size_t)(ch * BB + b) * (CC * TT);
        g0 += gp[tid];
        g1 += gp[tid + 1024];
    }
    Gs[tid] = g0;
    Gs[tid + 1024] = g1;
    __syncthreads();

    float sc = be[t * TT + u];
#pragma unroll
    for (int c = 0; c < CC; ++c) {
        sc += As[t][c] * Gs[c * TT + u];
    }
    sig[t][u] = 1.f / (1.f + __expf(-sc));
    __syncthreads();

    float e = 0.f;
#pragma unroll
    for (int s = 0; s < TT; ++s) {
        e += Ve[t * TT + s] * sig[s][u];
    }
    e0[t][u] = e;
    __syncthreads();

    float m = -1e30f;
#pragma unroll
    for (int tt = 0; tt < TT; ++tt) m = fmaxf(m, e0[tt][u]);
    float mysig = __expf(e - m);
    float sum = 0.f;
#pragma unroll
    for (int tt = 0; tt < TT; ++tt) sum += __expf(e0[tt][u] - m);
    E[((size_t)b * TT + t) * TT + u] = mysig / sum;
}

// ---------------- X_hat[b,n,c,s] = sum_t X[b,n,c,t] * E[b,t,s] ----------------
// Input AND output staged through one XOR-swizzled LDS tile:
//   A: contiguous cached global reads (each line touched once) -> swizzled LDS
//   B: per-thread row from thread-private LDS slots; compute in registers
//   C: result row back into the SAME thread-private slots (no barrier needed)
//   D: contiguous nt-stores (no partial-line RFO)
__global__ __launch_bounds__(256) void k_xhat(const float* __restrict__ X,
                                              const float* __restrict__ E,
                                              float* __restrict__ Y) {
    const int blocks_per_b = (NN * CC) / 256;  // 250
    int b = blockIdx.x / blocks_per_b;
    int tid = threadIdx.x;
    size_t qbase = (size_t)blockIdx.x * 2048;  // block tile = 2048 float4 quads

    __shared__ floatx4 ly[256 * 8];  // 32 KB

    // Phase A: contiguous global read -> swizzled LDS write (lines touched once)
    const floatx4* Xq = (const floatx4*)X;
#pragma unroll
    for (int k = 0; k < 8; ++k) {
        int g = k * 256 + tid;
        int lr = g >> 3;
        int q = g & 7;
        ly[lr * 8 + (q ^ (lr & 7))] = Xq[qbase + g];
    }
    __syncthreads();

    // Phase B: thread's row from its own LDS slots
    float x[TT];
#pragma unroll
    for (int j = 0; j < 8; ++j) {
        floatx4 v = ly[tid * 8 + (j ^ (tid & 7))];
        x[4 * j + 0] = v.x; x[4 * j + 1] = v.y;
        x[4 * j + 2] = v.z; x[4 * j + 3] = v.w;
    }

    const float* Eb = E + (size_t)b * TT * TT;
    float acc[TT];
#pragma unroll
    for (int s = 0; s < TT; ++s) acc[s] = 0.f;
#pragma unroll 4
    for (int t = 0; t < TT; ++t) {
        float xt = x[t];
#pragma unroll
        for (int s = 0; s < TT; ++s) {
            acc[s] += xt * Eb[t * TT + s];
        }
    }

    // Phase C: result row back into the same thread-private slots (no sync needed)
#pragma unroll
    for (int q = 0; q < 8; ++q) {
        floatx4 v = { acc[4 * q + 0], acc[4 * q + 1],
                      acc[4 * q + 2], acc[4 * q + 3] };
        ly[tid * 8 + (q ^ (tid & 7))] = v;
    }
    __syncthreads();

    // Phase D: contiguous nt-stores
    floatx4* Yq = (floatx4*)Y;
#pragma unroll
    for (int k = 0; k < 8; ++k) {
        int g = k * 256 + tid;
        int lr = g >> 3;
        int q = g & 7;
        floatx4 v = ly[lr * 8 + (q ^ (lr & 7))];
        __builtin_nontemporal_store(v, &Yq[qbase + g]);
    }
}

extern "C" void kernel_launch(void* const* d_in, const int* in_sizes, int n_in,
                              void* d_out, int out_size, void* d_ws, size_t ws_size,
                              hipStream_t stream) {
    const float* X  = (const float*)d_in[0];
    const float* U1 = (const float*)d_in[1];
    const float* U2 = (const float*)d_in[2];
    const float* U3 = (const float*)d_in[3];
    const float* be = (const float*)d_in[4];
    const float* Ve = (const float*)d_in[5];
    float* Y = (float*)d_out;

    // workspace carve (floats): Apart | Gpart | E  (~26.5 MB)
    float* Apart = (float*)d_ws;
    float* Gpart = Apart + (size_t)NCHUNKS * BB * TT * CC;     // +3,276,800
    float* E     = Gpart + (size_t)NCHUNKS * BB * CC * TT;     // +3,276,800

    k_p1<<<BB * NCHUNKS, 256, 0, stream>>>(X, U1, U3, U2, Apart, Gpart);
    k_E<<<BB, 1024, 0, stream>>>(Apart, Gpart, be, Ve, E);
    k_xhat<<<BB * ((NN * CC) / 256), 256, 0, stream>>>(X, E, Y);
}

// Round 8
// 334.659 us; speedup vs baseline: 1.0722x; 1.0722x over previous
//
#include <hip/hip_runtime.h>
#include <math.h>

#define BB 64
#define NN 1000
#define CC 64
#define TT 32
#define NCH 40
#define NCHUNKS 25   // NN / NCH

typedef float floatx4 __attribute__((ext_vector_type(4)));

// ---- Fused pass 1: one read of X -> Apart chunk-partials + Gpart chunk-partials ----
// grid = BB * NCHUNKS blocks, 256 threads.
// Thread (t = tid&31, nl = tid>>5): owns c-half (nl&1) and n-group (nl>>1).
// Per n (10 per thread): 32 scalar loads of its c-half;
//   rhs: r_half = sum_{c in half} U3[c]*x;  full r = r_half + shfl_xor(r_half,32)
//        (pair threads nl, nl^1 are lanes l and l+32 of the same wave)
//   A:   accA[cc] += U1[n]*x   (32 accumulators -> ~half the VGPR of before)
// Tail: in-block mini-GEMM for Gpart, then 4-deep A-reduction over n-groups.
__global__ __launch_bounds__(256) void k_p1(const float* __restrict__ X,
                                            const float* __restrict__ U1,
                                            const float* __restrict__ U3,
                                            const float* __restrict__ U2,
                                            float* __restrict__ Apart,
                                            float* __restrict__ Gpart) {
    int b  = blockIdx.x / NCHUNKS;
    int ch = blockIdx.x % NCHUNKS;
    int t  = threadIdx.x & 31;
    int nl = threadIdx.x >> 5;
    int w  = nl >> 1;        // n-group 0..3 (== wave id)
    int half = nl & 1;       // c-half 0..1
    int n0 = ch * NCH;

    __shared__ float u2s[CC][NCH + 1];    // 10.5 KB
    __shared__ float rls[NCH][TT];        // 5 KB
    __shared__ float abuf[4][32][17];     // 8.7 KB  [w][t][half*8 + j], pad 17

    // stage U2 chunk: u2s[c][n] = U2[c, n0+n]
    for (int k = threadIdx.x; k < CC * NCH; k += 256) {
        int c = k / NCH, n = k % NCH;
        u2s[c][n] = U2[(size_t)c * NN + n0 + n];
    }

    const float* U3h = U3 + half * 32;
    float accA[32];
#pragma unroll
    for (int cc = 0; cc < 32; ++cc) accA[cc] = 0.f;

    for (int i = 0; i < NCH / 4; ++i) {
        int n = n0 + i * 4 + w;
        const float* xp = X + ((size_t)(b * NN + n) * CC + half * 32) * TT + t;
        float u1 = U1[n];
        float r = 0.f;
#pragma unroll
        for (int cc = 0; cc < 32; ++cc) {
            float x = __builtin_nontemporal_load(&xp[cc * TT]);
            r += U3h[cc] * x;
            accA[cc] += u1 * x;
        }
        r += __shfl_xor(r, 32);
        if (half == 0) rls[i * 4 + w][t] = r;
    }
    __syncthreads();  // covers u2s staging + rls writes

    // mini-GEMM: thread -> c = tid>>2, s0 = (tid&3)*8; 8 outputs
    {
        int c = threadIdx.x >> 2;
        int s0 = (threadIdx.x & 3) * 8;
        float g[8];
#pragma unroll
        for (int j = 0; j < 8; ++j) g[j] = 0.f;
#pragma unroll 4
        for (int n = 0; n < NCH; ++n) {
            float u2v = u2s[c][n];
            floatx4 r0 = *(const floatx4*)&rls[n][s0];
            floatx4 r1 = *(const floatx4*)&rls[n][s0 + 4];
            g[0] += u2v * r0.x; g[1] += u2v * r0.y;
            g[2] += u2v * r0.z; g[3] += u2v * r0.w;
            g[4] += u2v * r1.x; g[5] += u2v * r1.y;
            g[6] += u2v * r1.z; g[7] += u2v * r1.w;
        }
        float* gp = Gpart + ((size_t)(ch * BB + b) * CC + c) * TT + s0;
        floatx4 v0 = { g[0], g[1], g[2], g[3] };
        floatx4 v1 = { g[4], g[5], g[6], g[7] };
        *(floatx4*)gp = v0;
        *(floatx4*)(gp + 4) = v1;
    }

    // A-reduction: 4 strips of 8 cc's; partials over 4 n-groups via abuf
    int t2 = threadIdx.x & 31;
    int j2 = threadIdx.x >> 5;   // 0..7
    for (int strip = 0; strip < 4; ++strip) {
        __syncthreads();
#pragma unroll
        for (int j = 0; j < 8; ++j) abuf[w][t][half * 8 + j] = accA[strip * 8 + j];
        __syncthreads();
#pragma unroll
        for (int ch2 = 0; ch2 < 2; ++ch2) {
            float v = abuf[0][t2][ch2 * 8 + j2] + abuf[1][t2][ch2 * 8 + j2]
                    + abuf[2][t2][ch2 * 8 + j2] + abuf[3][t2][ch2 * 8 + j2];
            Apart[((size_t)(ch * BB + b) * TT + t2) * CC + ch2 * 32 + strip * 8 + j2] = v;
        }
    }
}

// ---- E[b,t,u]: reduce Apart & Gpart -> scores -> sigmoid -> Ve@ -> softmax ----
__global__ __launch_bounds__(1024) void k_E(const float* __restrict__ Apart,
                                            const float* __restrict__ Gpart,
                                            const float* __restrict__ be,
                                            const float* __restrict__ Ve,
                                            float* __restrict__ E) {
    int b = blockIdx.x;
    int tid = threadIdx.x;
    int u = tid & 31;
    int t = tid >> 5;
    __shared__ float As[TT][CC + 1];
    __shared__ float Gs[CC * TT];
    __shared__ float sig[TT][TT];
    __shared__ float e0[TT][TT];

    float a0 = 0.f, a1 = 0.f;
    for (int ch = 0; ch < NCHUNKS; ++ch) {
        const float* ap = Apart + ((size_t)(ch * BB + b) * TT + t) * CC;
        a0 += ap[u];
        a1 += ap[u + 32];
    }
    As[t][u] = a0;
    As[t][u + 32] = a1;

    float g0 = 0.f, g1 = 0.f;
    for (int ch = 0; ch < NCHUNKS; ++ch) {
        const float* gp = Gpart + (size_t)(ch * BB + b) * (CC * TT);
        g0 += gp[tid];
        g1 += gp[tid + 1024];
    }
    Gs[tid] = g0;
    Gs[tid + 1024] = g1;
    __syncthreads();

    float sc = be[t * TT + u];
#pragma unroll
    for (int c = 0; c < CC; ++c) {
        sc += As[t][c] * Gs[c * TT + u];
    }
    sig[t][u] = 1.f / (1.f + __expf(-sc));
    __syncthreads();

    float e = 0.f;
#pragma unroll
    for (int s = 0; s < TT; ++s) {
        e += Ve[t * TT + s] * sig[s][u];
    }
    e0[t][u] = e;
    __syncthreads();

    float m = -1e30f;
#pragma unroll
    for (int tt = 0; tt < TT; ++tt) m = fmaxf(m, e0[tt][u]);
    float mysig = __expf(e - m);
    float sum = 0.f;
#pragma unroll
    for (int tt = 0; tt < TT; ++tt) sum += __expf(e0[tt][u] - m);
    E[((size_t)b * TT + t) * TT + u] = mysig / sum;
}

// ---------------- X_hat[b,n,c,s] = sum_t X[b,n,c,t] * E[b,t,s] ----------------
// Round-6 form: direct per-thread row loads, stores transposed through
// XOR-swizzled LDS -> 1 KB-contiguous nt-stores (no partial-line RFO).
__global__ __launch_bounds__(256) void k_xhat(const float* __restrict__ X,
                                              const float* __restrict__ E,
                                              float* __restrict__ Y) {
    const int blocks_per_b = (NN * CC) / 256;  // 250
    int b = blockIdx.x / blocks_per_b;
    int tid = threadIdx.x;
    size_t row = (size_t)blockIdx.x * 256 + tid;  // global (b,n,c) row
    const float* xp = X + row * TT;
    float x[TT];
#pragma unroll
    for (int j = 0; j < TT / 4; ++j) {
        floatx4 v = *(const floatx4*)(xp + 4 * j);
        x[4 * j + 0] = v.x; x[4 * j + 1] = v.y;
        x[4 * j + 2] = v.z; x[4 * j + 3] = v.w;
    }
    const float* Eb = E + (size_t)b * TT * TT;
    float acc[TT];
#pragma unroll
    for (int s = 0; s < TT; ++s) acc[s] = 0.f;
#pragma unroll 4
    for (int t = 0; t < TT; ++t) {
        float xt = x[t];
#pragma unroll
        for (int s = 0; s < TT; ++s) {
            acc[s] += xt * Eb[t * TT + s];
        }
    }

    __shared__ floatx4 ly[256 * 8];  // 32 KB
#pragma unroll
    for (int q = 0; q < 8; ++q) {
        floatx4 v = { acc[4 * q + 0], acc[4 * q + 1],
                      acc[4 * q + 2], acc[4 * q + 3] };
        ly[tid * 8 + (q ^ (tid & 7))] = v;
    }
    __syncthreads();

    floatx4* Yq = (floatx4*)Y;
    size_t qbase = (size_t)blockIdx.x * 2048;
#pragma unroll
    for (int k = 0; k < 8; ++k) {
        int g = k * 256 + tid;
        int lr = g >> 3;
        int q = g & 7;
        floatx4 v = ly[lr * 8 + (q ^ (lr & 7))];
        __builtin_nontemporal_store(v, &Yq[qbase + g]);
    }
}

extern "C" void kernel_launch(void* const* d_in, const int* in_sizes, int n_in,
                              void* d_out, int out_size, void* d_ws, size_t ws_size,
                              hipStream_t stream) {
    const float* X  = (const float*)d_in[0];
    const float* U1 = (const float*)d_in[1];
    const float* U2 = (const float*)d_in[2];
    const float* U3 = (const float*)d_in[3];
    const float* be = (const float*)d_in[4];
    const float* Ve = (const float*)d_in[5];
    float* Y = (float*)d_out;

    // workspace carve (floats): Apart | Gpart | E  (~26.5 MB)
    float* Apart = (float*)d_ws;
    float* Gpart = Apart + (size_t)NCHUNKS * BB * TT * CC;     // +3,276,800
    float* E     = Gpart + (size_t)NCHUNKS * BB * CC * TT;     // +3,276,800

    k_p1<<<BB * NCHUNKS, 256, 0, stream>>>(X, U1, U3, U2, Apart, Gpart);
    k_E<<<BB, 1024, 0, stream>>>(Apart, Gpart, be, Ve, E);
    k_xhat<<<BB * ((NN * CC) / 256), 256, 0, stream>>>(X, E, Y);
}